// Round 8
// baseline (2338.148 us; speedup 1.0000x reference)
//
#include <hip/hip_runtime.h>
#include <hip/hip_bf16.h>

// ---------- types ----------
typedef __attribute__((ext_vector_type(8))) short bf16x8;
typedef __attribute__((ext_vector_type(4))) float f32x4;
typedef __attribute__((ext_vector_type(4))) unsigned int u32x4;

__device__ __forceinline__ short f2b(float f) {
    unsigned u = __builtin_bit_cast(unsigned, f);
    unsigned r = (u + 0x7fffu + ((u >> 16) & 1u)) >> 16;
    return (short)r;
}
__device__ __forceinline__ unsigned f2bu(float f) {
    unsigned u = __builtin_bit_cast(unsigned, f);
    return ((u + 0x7fffu + ((u >> 16) & 1u)) >> 16) & 0xffffu;
}
__device__ __forceinline__ float blo(unsigned u) {
    return __builtin_bit_cast(float, u << 16);
}
__device__ __forceinline__ float bhi(unsigned u) {
    return __builtin_bit_cast(float, u & 0xffff0000u);
}

// =====================================================================
// Weight pre-conversion: fp32 -> bf16 in MFMA fragment order.
// =====================================================================
__global__ __launch_bounds__(256) void wprep(
    const float* __restrict__ W_in, const float* __restrict__ W_out,
    unsigned short* __restrict__ Wi_f, unsigned short* __restrict__ Wo_f)
{
    int o = blockIdx.x * 256 + threadIdx.x;
    if (o < 131072) {
        int j = o & 7, lane = (o >> 3) & 63, t = (o >> 9) & 15, kk = o >> 13;
        int n = t * 16 + (lane & 15);
        int k = kk * 32 + ((lane >> 4) << 3) + j;
        Wi_f[o] = (unsigned short)f2bu(W_in[n * 512 + k]);
    } else if (o < 131072 + 16384) {
        int o2 = o - 131072;
        int j = o2 & 7, lane = (o2 >> 3) & 63, t = (o2 >> 9) & 3, kk2 = o2 >> 11;
        int n = t * 16 + (lane & 15);
        int k = kk2 * 32 + ((lane >> 4) << 3) + j;
        Wo_f[o2] = (unsigned short)f2bu(W_out[n * 256 + k]);
    }
}

// =====================================================================
// Fused MLP: z0 = relu(x @ W_in^T + b_in) @ W_out^T + b_out  -> bf16
// (unchanged: A in regs, B double-buffered DMA, 1 barrier/K-step;
//  z0 row-major [N][64] coalesced write)
// =====================================================================
__global__ __launch_bounds__(256) void mlp(
    const float* __restrict__ x, const unsigned short* __restrict__ Wi_f,
    const float* __restrict__ b_in, const unsigned short* __restrict__ Wo_f,
    const float* __restrict__ b_out, unsigned short* __restrict__ z0, int M)
{
    __shared__ __align__(16) char smem[33280];
    short* Bt0 = (short*)smem;            // frag-ordered [t<16][lane<64][j<8]
    short* Bt1 = (short*)(smem + 16384);
    short* Hs  = (short*)smem;            // stage2: [qb<32][520] (aliases Bt)

    const int tid  = threadIdx.x;
    const int lane = tid & 63;
    const int w    = tid >> 6;
    const int row0 = blockIdx.x * 64;
    const int c    = lane & 15;
    const int qk   = lane >> 4;

    const int growA = row0 + 16 * w + c;
    const float* xrow = x + (size_t)(growA < M ? growA : (M - 1)) * 512 + qk * 8;

    f32x4 acc[16];
#pragma unroll
    for (int t = 0; t < 16; ++t) { acc[t][0]=0.f; acc[t][1]=0.f; acc[t][2]=0.f; acc[t][3]=0.f; }

    float4 av0 = *(const float4*)(xrow);
    float4 av1 = *(const float4*)(xrow + 4);
#pragma unroll
    for (int i = 0; i < 4; ++i) {
        int t = w * 4 + i;
        const unsigned short* g = Wi_f + ((size_t)t * 64 + lane) * 8;
        __builtin_amdgcn_global_load_lds(
            (const __attribute__((address_space(1))) unsigned int*)g,
            (__attribute__((address_space(3))) unsigned int*)(Bt0 + t * 512),
            16, 0, 0);
    }
    __syncthreads();

    for (int kk = 0; kk < 16; ++kk) {
        short* Bc = (kk & 1) ? Bt1 : Bt0;
        short* Bn = (kk & 1) ? Bt0 : Bt1;
        float4 a0 = av0, a1 = av1;
        if (kk < 15) {
            const float* xn = xrow + (kk + 1) * 32;
            av0 = *(const float4*)(xn);
            av1 = *(const float4*)(xn + 4);
#pragma unroll
            for (int i = 0; i < 4; ++i) {
                int t = w * 4 + i;
                const unsigned short* g = Wi_f + (((size_t)(kk + 1) * 16 + t) * 64 + lane) * 8;
                __builtin_amdgcn_global_load_lds(
                    (const __attribute__((address_space(1))) unsigned int*)g,
                    (__attribute__((address_space(3))) unsigned int*)(Bn + t * 512),
                    16, 0, 0);
            }
        }
        bf16x8 a;
        a[0] = (short)f2bu(a0.x); a[1] = (short)f2bu(a0.y);
        a[2] = (short)f2bu(a0.z); a[3] = (short)f2bu(a0.w);
        a[4] = (short)f2bu(a1.x); a[5] = (short)f2bu(a1.y);
        a[6] = (short)f2bu(a1.z); a[7] = (short)f2bu(a1.w);
#pragma unroll
        for (int t = 0; t < 16; ++t) {
            bf16x8 b = *(const bf16x8*)(Bc + (t * 64 + lane) * 8);
            acc[t] = __builtin_amdgcn_mfma_f32_16x16x32_bf16(a, b, acc[t], 0, 0, 0);
        }
        __syncthreads();
    }

#pragma unroll
    for (int t = 0; t < 16; ++t) {
        int col = 16 * t + c;
        float bv = b_in[col];
        int qb = col >> 3, j = col & 7;
#pragma unroll
        for (int r = 0; r < 4; ++r) {
            int row = 16 * w + qk * 4 + r;
            float h = acc[t][r] + bv;
            h = h > 0.f ? h : 0.f;
            Hs[qb * 520 + row * 8 + j] = f2b(h);
        }
    }
    __syncthreads();
    f32x4 acc2[4];
#pragma unroll
    for (int t = 0; t < 4; ++t) { acc2[t][0]=0.f; acc2[t][1]=0.f; acc2[t][2]=0.f; acc2[t][3]=0.f; }
#pragma unroll
    for (int kk2 = 0; kk2 < 8; ++kk2) {
        bf16x8 a2 = *(const bf16x8*)(Hs + (kk2 * 4 + qk) * 520 + (16 * w + c) * 8);
#pragma unroll
        for (int t = 0; t < 4; ++t) {
            bf16x8 b2 = *(const bf16x8*)(Wo_f + (((size_t)kk2 * 4 + t) * 64 + lane) * 8);
            acc2[t] = __builtin_amdgcn_mfma_f32_16x16x32_bf16(a2, b2, acc2[t], 0, 0, 0);
        }
    }
#pragma unroll
    for (int t = 0; t < 4; ++t) {
        int col = 16 * t + c;
        float bv = b_out[col];
#pragma unroll
        for (int r = 0; r < 4; ++r) {
            int grow = row0 + 16 * w + qk * 4 + r;
            if (grow < M) z0[(size_t)grow * 64 + col] = (unsigned short)f2bu(acc2[t][r] + bv);
        }
    }
}

// =====================================================================
// CSR build: 2-level counting sort by (src-stripe, dst).
// Key: coarse = stripe*nb1 + (dst>>11); fine = dst within 2048-node range.
// Produces rowptr4[stripe*N + node] — per-(stripe,node) segment bounds.
// =====================================================================
#define CSR_CH   16384
#define MAXBUK   256
#define FB       2048

__global__ __launch_bounds__(256) void coarse_hist(
    const int* __restrict__ src, const int* __restrict__ dst,
    int* __restrict__ M, int E, int nbuk2, int nb1, int qs)
{
    __shared__ int cnt[MAXBUK];
    int tid = threadIdx.x, blk = blockIdx.x;
    for (int i = tid; i < nbuk2; i += 256) cnt[i] = 0;
    __syncthreads();
    int e0 = blk * CSR_CH, e1 = e0 + CSR_CH; if (e1 > E) e1 = E;
    for (int e = e0 + tid; e < e1; e += 256) {
        int key = (src[e] / qs) * nb1 + (dst[e] >> 11);
        atomicAdd(&cnt[key], 1);
    }
    __syncthreads();
    for (int i = tid; i < nbuk2; i += 256) M[blk * nbuk2 + i] = cnt[i];
}

__global__ __launch_bounds__(256) void bucket_scan(
    int* __restrict__ M, int* __restrict__ bucketBase, int nblk, int nbuk2)
{
    __shared__ int tot[MAXBUK];
    int tid = threadIdx.x;
    for (int r = tid; r < nbuk2; r += 256) {
        int s = 0;
        for (int k = 0; k < nblk; ++k) s += M[k * nbuk2 + r];
        tot[r] = s;
    }
    __syncthreads();
    if (tid == 0) {
        int s = 0;
        for (int r = 0; r < nbuk2; ++r) { int t = tot[r]; tot[r] = s; bucketBase[r] = s; s += t; }
        bucketBase[nbuk2] = s;
    }
    __syncthreads();
    for (int r = tid; r < nbuk2; r += 256) {
        int s = tot[r];
        for (int k = 0; k < nblk; ++k) { int t = M[k * nbuk2 + r]; M[k * nbuk2 + r] = s; s += t; }
    }
}

__global__ __launch_bounds__(256) void coarse_scatter(
    const int* __restrict__ src, const int* __restrict__ dst,
    const float* __restrict__ ew, const int* __restrict__ M,
    int4* __restrict__ tmp, int E, int nbuk2, int nb1, int qs)
{
    __shared__ int off[MAXBUK];
    int tid = threadIdx.x, blk = blockIdx.x;
    for (int i = tid; i < nbuk2; i += 256) off[i] = M[blk * nbuk2 + i];
    __syncthreads();
    int e0 = blk * CSR_CH, e1 = e0 + CSR_CH; if (e1 > E) e1 = E;
    for (int e = e0 + tid; e < e1; e += 256) {
        int s = src[e], d = dst[e];
        int key = (s / qs) * nb1 + (d >> 11);
        int pos = atomicAdd(&off[key], 1);
        tmp[pos] = make_int4(s, __builtin_bit_cast(int, ew[e]), d, 0);
    }
}

__global__ __launch_bounds__(256) void fine_sort(
    const int4* __restrict__ tmp, const int* __restrict__ bucketBase,
    int2* __restrict__ csr, int* __restrict__ rowptr4,
    int N, int E, int nb1)
{
    __shared__ int fc[FB];
    __shared__ int fo[FB];
    __shared__ int wsum[5];
    int b = blockIdx.x, tid = threadIdx.x;
    int base = bucketBase[b], cnt = bucketBase[b + 1] - base;
    int stripe = b / nb1;
    int node0  = (b % nb1) << 11;

    for (int i = tid; i < FB; i += 256) fc[i] = 0;
    __syncthreads();
    for (int i = tid; i < cnt; i += 256)
        atomicAdd(&fc[tmp[base + i].z - node0], 1);
    __syncthreads();

    int lane = tid & 63, wid = tid >> 6;
    int runbase = 0;
    for (int h = 0; h < FB / 256; ++h) {
        int v = fc[h * 256 + tid];
        int x = v;
#pragma unroll
        for (int off = 1; off < 64; off <<= 1) { int y = __shfl_up(x, off); if (lane >= off) x += y; }
        if (lane == 63) wsum[wid] = x;
        __syncthreads();
        if (tid == 0) { int s = 0; for (int k = 0; k < 4; ++k) { int t = wsum[k]; wsum[k] = s; s += t; } wsum[4] = s; }
        __syncthreads();
        fo[h * 256 + tid] = runbase + wsum[wid] + x - v;
        runbase += wsum[4];
        __syncthreads();
    }

    for (int i = tid; i < FB; i += 256) {
        int node = node0 + i;
        if (node < N) rowptr4[(size_t)stripe * N + node] = base + fo[i];
    }
    if (b == 0 && tid == 0) rowptr4[(size_t)4 * N] = E;
    __syncthreads();

    for (int i = tid; i < cnt; i += 256) {
        int4 ed = tmp[base + i];
        int pos = atomicAdd(&fo[ed.z - node0], 1);
        csr[base + pos] = make_int2(ed.x, ed.y);
    }
}

// =====================================================================
// Striped propagation pass: zacc[node] (+)= 0.9 * sum_{e in stripe s}
// w_e * zin[src_e]; pass 0 initializes with 0.1*z0 blend; pass 3 emits.
// R0 gather structure: wave = node, 8 lanes x 16 B full-row gathers
// (cached — these are the ONLY L2-allocating loads; the stripe's 3.2 MB
// src window stays resident).  ALL streams (csr, z0, zacc, zout) are
// NT + wave-coalesced single-use (R2-proven safe NT pattern).
// =====================================================================
__global__ __launch_bounds__(256) void prop_stripe(
    const int* __restrict__ rowptr4, const int2* __restrict__ csr,
    const unsigned short* __restrict__ zin, const unsigned short* __restrict__ z0,
    float* __restrict__ zacc, unsigned short* __restrict__ zout_b,
    float* __restrict__ zout_f, int n, int s, int final_layer)
{
    int lane = threadIdx.x & 63;
    int node = blockIdx.x * 4 + (threadIdx.x >> 6);
    if (node >= n) return;
    const int* rp = rowptr4 + (size_t)s * n;
    int beg = rp[node], end = rp[node + 1];
    const int sub = lane >> 3;
    const int k8  = lane & 7;

    float acc[8];
#pragma unroll
    for (int i = 0; i < 8; ++i) acc[i] = 0.f;

    const long long* cp = (const long long*)csr;
    for (int b = beg; b < end; b += 64) {
        int e = b + lane;
        long long edp = (e < end) ? __builtin_nontemporal_load(cp + e) : 0ll;
        int edx = (int)edp;
        int edy = (int)(edp >> 32);
        int cnt = end - b; if (cnt > 64) cnt = 64;
        int groups = (cnt + 7) >> 3;
        for (int j = 0; j < groups; ++j) {
            int idx = j * 8 + sub;
            int sj = __shfl(edx, idx);
            int wb = __shfl(edy, idx);
            if (idx < cnt) {
                float wj = __builtin_bit_cast(float, wb);
                uint4 v = *(const uint4*)(zin + (size_t)sj * 64 + k8 * 8);
                acc[0] += wj * blo(v.x); acc[1] += wj * bhi(v.x);
                acc[2] += wj * blo(v.y); acc[3] += wj * bhi(v.y);
                acc[4] += wj * blo(v.z); acc[5] += wj * bhi(v.z);
                acc[6] += wj * blo(v.w); acc[7] += wj * bhi(v.w);
            }
        }
    }
#pragma unroll
    for (int off = 8; off < 64; off <<= 1) {
#pragma unroll
        for (int i = 0; i < 8; ++i) acc[i] += __shfl_xor(acc[i], off);
    }
    if (sub == 0) {
        float* zp = zacc + (size_t)node * 64 + k8 * 8;
        if (s == 0) {
            u32x4 zv = __builtin_nontemporal_load(
                (const u32x4*)(z0 + (size_t)node * 64 + k8 * 8));
            f32x4 lo, hi;
            lo[0] = 0.9f * acc[0] + 0.1f * blo(zv.x);
            lo[1] = 0.9f * acc[1] + 0.1f * bhi(zv.x);
            lo[2] = 0.9f * acc[2] + 0.1f * blo(zv.y);
            lo[3] = 0.9f * acc[3] + 0.1f * bhi(zv.y);
            hi[0] = 0.9f * acc[4] + 0.1f * blo(zv.z);
            hi[1] = 0.9f * acc[5] + 0.1f * bhi(zv.z);
            hi[2] = 0.9f * acc[6] + 0.1f * blo(zv.w);
            hi[3] = 0.9f * acc[7] + 0.1f * bhi(zv.w);
            __builtin_nontemporal_store(lo, (f32x4*)zp);
            __builtin_nontemporal_store(hi, (f32x4*)(zp + 4));
        } else {
            f32x4 p0 = __builtin_nontemporal_load((const f32x4*)zp);
            f32x4 p1 = __builtin_nontemporal_load((const f32x4*)(zp + 4));
            float o0 = p0[0] + 0.9f * acc[0];
            float o1 = p0[1] + 0.9f * acc[1];
            float o2 = p0[2] + 0.9f * acc[2];
            float o3 = p0[3] + 0.9f * acc[3];
            float o4 = p1[0] + 0.9f * acc[4];
            float o5 = p1[1] + 0.9f * acc[5];
            float o6 = p1[2] + 0.9f * acc[6];
            float o7 = p1[3] + 0.9f * acc[7];
            if (s < 3) {
                f32x4 lo, hi;
                lo[0]=o0; lo[1]=o1; lo[2]=o2; lo[3]=o3;
                hi[0]=o4; hi[1]=o5; hi[2]=o6; hi[3]=o7;
                __builtin_nontemporal_store(lo, (f32x4*)zp);
                __builtin_nontemporal_store(hi, (f32x4*)(zp + 4));
            } else if (final_layer) {
                float* dp = zout_f + (size_t)node * 64 + k8 * 8;
                *(float4*)dp       = make_float4(o0, o1, o2, o3);
                *(float4*)(dp + 4) = make_float4(o4, o5, o6, o7);
            } else {
                u32x4 pv;
                pv.x = f2bu(o0) | (f2bu(o1) << 16);
                pv.y = f2bu(o2) | (f2bu(o3) << 16);
                pv.z = f2bu(o4) | (f2bu(o5) << 16);
                pv.w = f2bu(o6) | (f2bu(o7) << 16);
                __builtin_nontemporal_store(
                    pv, (u32x4*)(zout_b + (size_t)node * 64 + k8 * 8));
            }
        }
    }
}

// =====================================================================
static inline size_t align_up(size_t v, size_t a) { return (v + a - 1) & ~(a - 1); }

extern "C" void kernel_launch(void* const* d_in, const int* in_sizes, int n_in,
                              void* d_out, int out_size, void* d_ws, size_t ws_size,
                              hipStream_t stream)
{
    const float* x     = (const float*)d_in[0];
    const float* W_in  = (const float*)d_in[1];
    const float* b_in  = (const float*)d_in[2];
    const float* W_out = (const float*)d_in[3];
    const float* b_out = (const float*)d_in[4];
    const int*   ei    = (const int*)d_in[5];     // [2,E]: src then dst
    const float* ew    = (const float*)d_in[6];

    const int N = in_sizes[0] / 512;              // 100000
    const int E = in_sizes[6];                    // 3200000
    const int* e_src = ei;
    const int* e_dst = ei + E;

    const int qs    = (N + 3) / 4;                // src-stripe quotient (25000)
    const int nb1   = (N + FB - 1) / FB;          // dst ranges per stripe (49)
    const int nbuk2 = 4 * nb1;                    // coarse buckets (196)
    const int nblk  = (E + CSR_CH - 1) / CSR_CH;  // 196

    // ---- workspace carve-up ----
    char* p = (char*)d_ws;
    size_t zbytes = align_up((size_t)N * 64 * sizeof(unsigned short), 256);
    unsigned short* z0b = (unsigned short*)p; p += zbytes;
    unsigned short* Wi_f = (unsigned short*)p; p += align_up(131072 * 2, 256);
    unsigned short* Wo_f = (unsigned short*)p; p += align_up(16384 * 2, 256);
    int2* csr    = (int2*)p; p += align_up((size_t)E * 8, 256);
    int* rowptr4 = (int*)p;  p += align_up(((size_t)4 * N + 1) * 4, 256);
    int* M       = (int*)p;  p += align_up((size_t)nblk * nbuk2 * 4, 256);
    int* bucketBase = (int*)p; p += align_up((size_t)(nbuk2 + 1) * 4, 256);
    int4* tmp    = (int4*)p; p += align_up((size_t)E * 16, 256);
    // overlays inside tmp (dead after fine_sort): bf16 ping-pong + fp32 acc
    unsigned short* zA   = (unsigned short*)tmp;            // 12.8 MB
    unsigned short* zB   = zA + (size_t)N * 64;             // 12.8 MB
    float*          zacc = (float*)(zB + (size_t)N * 64);   // 25.6 MB (=51.2 total = E*16)

    // ---- weights -> bf16 fragment order, then MLP -> z0 (bf16 row-major) ----
    wprep<<<(131072 + 16384 + 255) / 256, 256, 0, stream>>>(W_in, W_out, Wi_f, Wo_f);
    mlp<<<(N + 63) / 64, 256, 0, stream>>>(x, Wi_f, b_in, Wo_f, b_out, z0b, N);

    // ---- CSR build: 2-level counting sort by (src-stripe, dst) ----
    coarse_hist<<<nblk, 256, 0, stream>>>(e_src, e_dst, M, E, nbuk2, nb1, qs);
    bucket_scan<<<1, 256, 0, stream>>>(M, bucketBase, nblk, nbuk2);
    coarse_scatter<<<nblk, 256, 0, stream>>>(e_src, e_dst, ew, M, tmp, E, nbuk2, nb1, qs);
    fine_sort<<<nbuk2, 256, 0, stream>>>(tmp, bucketBase, csr, rowptr4, N, E, nb1);

    // ---- 10 layers x 4 src-stripe passes ----
    float* out_f = (float*)d_out;
    int pgrid = (N + 3) / 4;
    for (int i = 0; i < 10; ++i) {
        const unsigned short* zin = (i == 0) ? z0b : ((i & 1) ? zA : zB);
        unsigned short* zoutb = (i & 1) ? zB : zA;
        for (int s = 0; s < 4; ++s) {
            prop_stripe<<<pgrid, 256, 0, stream>>>(rowptr4, csr, zin, z0b,
                                                   zacc, zoutb, out_f, N, s,
                                                   (i == 9) ? 1 : 0);
        }
    }
}

// Round 9
// 1149.667 us; speedup vs baseline: 2.0338x; 2.0338x over previous
//
#include <hip/hip_runtime.h>
#include <hip/hip_bf16.h>

// ---------- types ----------
typedef __attribute__((ext_vector_type(8))) short bf16x8;
typedef __attribute__((ext_vector_type(4))) float f32x4;
typedef __attribute__((ext_vector_type(4))) unsigned int u32x4;

__device__ __forceinline__ short f2b(float f) {
    unsigned u = __builtin_bit_cast(unsigned, f);
    unsigned r = (u + 0x7fffu + ((u >> 16) & 1u)) >> 16;
    return (short)r;
}
__device__ __forceinline__ unsigned f2bu(float f) {
    unsigned u = __builtin_bit_cast(unsigned, f);
    return ((u + 0x7fffu + ((u >> 16) & 1u)) >> 16) & 0xffffu;
}
// HW packed f32x2 -> bf16x2 (RNE, identical rounding to f2bu pair).
// No builtin on gfx950 -> inline asm (T12). Non-volatile: schedulable.
__device__ __forceinline__ unsigned cvtpk(float lo, float hi) {
    unsigned r;
    asm("v_cvt_pk_bf16_f32 %0, %1, %2" : "=v"(r) : "v"(lo), "v"(hi));
    return r;
}
__device__ __forceinline__ float blo(unsigned u) {
    return __builtin_bit_cast(float, u << 16);
}
__device__ __forceinline__ float bhi(unsigned u) {
    return __builtin_bit_cast(float, u & 0xffff0000u);
}

// =====================================================================
// Weight pre-conversion: fp32 -> bf16 in MFMA fragment order.
// Wi_f: [kk<16][t<16][lane<64][j<8]; Wo_f: [kk2<8][t<4][lane<64][j<8]
// =====================================================================
__global__ __launch_bounds__(256) void wprep(
    const float* __restrict__ W_in, const float* __restrict__ W_out,
    unsigned short* __restrict__ Wi_f, unsigned short* __restrict__ Wo_f)
{
    int o = blockIdx.x * 256 + threadIdx.x;
    if (o < 131072) {
        int j = o & 7, lane = (o >> 3) & 63, t = (o >> 9) & 15, kk = o >> 13;
        int n = t * 16 + (lane & 15);
        int k = kk * 32 + ((lane >> 4) << 3) + j;
        Wi_f[o] = (unsigned short)f2bu(W_in[n * 512 + k]);
    } else if (o < 131072 + 16384) {
        int o2 = o - 131072;
        int j = o2 & 7, lane = (o2 >> 3) & 63, t = (o2 >> 9) & 3, kk2 = o2 >> 11;
        int n = t * 16 + (lane & 15);
        int k = kk2 * 32 + ((lane >> 4) << 3) + j;
        Wo_f[o2] = (unsigned short)f2bu(W_out[n * 256 + k]);
    }
}

// =====================================================================
// Fused MLP: z0 = relu(x @ W_in^T + b_in) @ W_out^T + b_out  -> bf16
// A in regs (v_cvt_pk_bf16_f32 pack: 4 insts vs ~80 VALU ops/K-step),
// B double-buffered global_load_lds DMA, 1 barrier/K-step.
// z0 row-major [N][64] coalesced write.
// =====================================================================
__global__ __launch_bounds__(256) void mlp(
    const float* __restrict__ x, const unsigned short* __restrict__ Wi_f,
    const float* __restrict__ b_in, const unsigned short* __restrict__ Wo_f,
    const float* __restrict__ b_out, unsigned short* __restrict__ z0, int M)
{
    __shared__ __align__(16) char smem[33280];
    short* Bt0 = (short*)smem;            // frag-ordered [t<16][lane<64][j<8]
    short* Bt1 = (short*)(smem + 16384);
    short* Hs  = (short*)smem;            // stage2: [qb<32][520] (aliases Bt)

    const int tid  = threadIdx.x;
    const int lane = tid & 63;
    const int w    = tid >> 6;
    const int row0 = blockIdx.x * 64;
    const int c    = lane & 15;
    const int qk   = lane >> 4;

    const int growA = row0 + 16 * w + c;
    const float* xrow = x + (size_t)(growA < M ? growA : (M - 1)) * 512 + qk * 8;

    f32x4 acc[16];
#pragma unroll
    for (int t = 0; t < 16; ++t) { acc[t][0]=0.f; acc[t][1]=0.f; acc[t][2]=0.f; acc[t][3]=0.f; }

    // ---- prologue: issue A(0) + B(0) ----
    float4 av0 = *(const float4*)(xrow);
    float4 av1 = *(const float4*)(xrow + 4);
#pragma unroll
    for (int i = 0; i < 4; ++i) {
        int t = w * 4 + i;
        const unsigned short* g = Wi_f + ((size_t)t * 64 + lane) * 8;
        __builtin_amdgcn_global_load_lds(
            (const __attribute__((address_space(1))) unsigned int*)g,
            (__attribute__((address_space(3))) unsigned int*)(Bt0 + t * 512),
            16, 0, 0);
    }
    __syncthreads();

    for (int kk = 0; kk < 16; ++kk) {
        short* Bc = (kk & 1) ? Bt1 : Bt0;
        short* Bn = (kk & 1) ? Bt0 : Bt1;
        float4 a0 = av0, a1 = av1;
        if (kk < 15) {
            const float* xn = xrow + (kk + 1) * 32;
            av0 = *(const float4*)(xn);
            av1 = *(const float4*)(xn + 4);
#pragma unroll
            for (int i = 0; i < 4; ++i) {
                int t = w * 4 + i;
                const unsigned short* g = Wi_f + (((size_t)(kk + 1) * 16 + t) * 64 + lane) * 8;
                __builtin_amdgcn_global_load_lds(
                    (const __attribute__((address_space(1))) unsigned int*)g,
                    (__attribute__((address_space(3))) unsigned int*)(Bn + t * 512),
                    16, 0, 0);
            }
        }
        // pack A fragment: 4x v_cvt_pk_bf16_f32 (RNE, == f2bu pair)
        u32x4 pk;
        pk.x = cvtpk(a0.x, a0.y);
        pk.y = cvtpk(a0.z, a0.w);
        pk.z = cvtpk(a1.x, a1.y);
        pk.w = cvtpk(a1.z, a1.w);
        bf16x8 a = __builtin_bit_cast(bf16x8, pk);
#pragma unroll
        for (int t = 0; t < 16; ++t) {
            bf16x8 b = *(const bf16x8*)(Bc + (t * 64 + lane) * 8);
            acc[t] = __builtin_amdgcn_mfma_f32_16x16x32_bf16(a, b, acc[t], 0, 0, 0);
        }
        __syncthreads();   // drains prefetch vmcnt + MFMA ds_reads; buffers swap
    }

    // bias + relu -> Hs (bf16, q-padded k-blocked layout)
#pragma unroll
    for (int t = 0; t < 16; ++t) {
        int col = 16 * t + c;
        float bv = b_in[col];
        int qb = col >> 3, j = col & 7;
#pragma unroll
        for (int r = 0; r < 4; ++r) {
            int row = 16 * w + qk * 4 + r;
            float h = acc[t][r] + bv;
            h = h > 0.f ? h : 0.f;
            Hs[qb * 520 + row * 8 + j] = f2b(h);
        }
    }
    __syncthreads();
    // stage 2: z0_tile = Hs @ W_out^T ; B-frags straight from global (L1/L2)
    f32x4 acc2[4];
#pragma unroll
    for (int t = 0; t < 4; ++t) { acc2[t][0]=0.f; acc2[t][1]=0.f; acc2[t][2]=0.f; acc2[t][3]=0.f; }
#pragma unroll
    for (int kk2 = 0; kk2 < 8; ++kk2) {
        bf16x8 a2 = *(const bf16x8*)(Hs + (kk2 * 4 + qk) * 520 + (16 * w + c) * 8);
#pragma unroll
        for (int t = 0; t < 4; ++t) {
            bf16x8 b2 = *(const bf16x8*)(Wo_f + (((size_t)kk2 * 4 + t) * 64 + lane) * 8);
            acc2[t] = __builtin_amdgcn_mfma_f32_16x16x32_bf16(a2, b2, acc2[t], 0, 0, 0);
        }
    }
    // row-major z0 write (coalesced)
#pragma unroll
    for (int t = 0; t < 4; ++t) {
        int col = 16 * t + c;
        float bv = b_out[col];
#pragma unroll
        for (int r = 0; r < 4; ++r) {
            int grow = row0 + 16 * w + qk * 4 + r;
            if (grow < M) z0[(size_t)grow * 64 + col] = (unsigned short)f2bu(acc2[t][r] + bv);
        }
    }
}

// =====================================================================
// CSR build: 2-level counting sort by dst.
// =====================================================================
#define CSR_CH   16384
#define MAXBUK   256

__global__ __launch_bounds__(256) void coarse_hist(
    const int* __restrict__ dst, int* __restrict__ M, int E, int nbuk)
{
    __shared__ int cnt[MAXBUK];
    int tid = threadIdx.x, blk = blockIdx.x;
    for (int i = tid; i < nbuk; i += 256) cnt[i] = 0;
    __syncthreads();
    int e0 = blk * CSR_CH, e1 = e0 + CSR_CH; if (e1 > E) e1 = E;
    for (int e = e0 + tid; e < e1; e += 256) atomicAdd(&cnt[dst[e] >> 9], 1);
    __syncthreads();
    for (int i = tid; i < nbuk; i += 256) M[blk * nbuk + i] = cnt[i];
}

__global__ __launch_bounds__(256) void bucket_scan(
    int* __restrict__ M, int* __restrict__ bucketBase, int nblk, int nbuk)
{
    __shared__ int tot[MAXBUK];
    int tid = threadIdx.x;
    for (int r = tid; r < nbuk; r += 256) {
        int s = 0;
        for (int k = 0; k < nblk; ++k) s += M[k * nbuk + r];
        tot[r] = s;
    }
    __syncthreads();
    if (tid == 0) {
        int s = 0;
        for (int r = 0; r < nbuk; ++r) { int t = tot[r]; tot[r] = s; bucketBase[r] = s; s += t; }
        bucketBase[nbuk] = s;
    }
    __syncthreads();
    for (int r = tid; r < nbuk; r += 256) {
        int s = tot[r];
        for (int k = 0; k < nblk; ++k) { int t = M[k * nbuk + r]; M[k * nbuk + r] = s; s += t; }
    }
}

__global__ __launch_bounds__(256) void coarse_scatter(
    const int* __restrict__ src, const int* __restrict__ dst,
    const float* __restrict__ ew, const int* __restrict__ M,
    int4* __restrict__ tmp, int E, int nbuk)
{
    __shared__ int off[MAXBUK];
    int tid = threadIdx.x, blk = blockIdx.x;
    for (int i = tid; i < nbuk; i += 256) off[i] = M[blk * nbuk + i];
    __syncthreads();
    int e0 = blk * CSR_CH, e1 = e0 + CSR_CH; if (e1 > E) e1 = E;
    for (int e = e0 + tid; e < e1; e += 256) {
        int d = dst[e];
        int pos = atomicAdd(&off[d >> 9], 1);
        tmp[pos] = make_int4(src[e], __builtin_bit_cast(int, ew[e]), d, 0);
    }
}

__global__ __launch_bounds__(256) void fine_sort(
    const int4* __restrict__ tmp, const int* __restrict__ bucketBase,
    int2* __restrict__ csr, int* __restrict__ rowptr, int N, int E)
{
    __shared__ int fc[512];
    __shared__ int fo[512];
    __shared__ int wsum[5];
    int b = blockIdx.x, tid = threadIdx.x;
    int base = bucketBase[b], cnt = bucketBase[b + 1] - base;
    int node0 = b << 9;

    fc[tid] = 0; fc[tid + 256] = 0;
    __syncthreads();
    for (int i = tid; i < cnt; i += 256)
        atomicAdd(&fc[tmp[base + i].z - node0], 1);
    __syncthreads();

    int lane = tid & 63, wid = tid >> 6;
    int runbase = 0;
    for (int h = 0; h < 2; ++h) {
        int v = fc[h * 256 + tid];
        int x = v;
#pragma unroll
        for (int off = 1; off < 64; off <<= 1) { int y = __shfl_up(x, off); if (lane >= off) x += y; }
        if (lane == 63) wsum[wid] = x;
        __syncthreads();
        if (tid == 0) { int s = 0; for (int k = 0; k < 4; ++k) { int t = wsum[k]; wsum[k] = s; s += t; } wsum[4] = s; }
        __syncthreads();
        fo[h * 256 + tid] = runbase + wsum[wid] + x - v;
        runbase += wsum[4];
        __syncthreads();
    }

    for (int i = tid; i < 512; i += 256) {
        int node = node0 + i;
        if (node < N) rowptr[node] = base + fo[i];
    }
    if (b == 0 && tid == 0) rowptr[N] = E;
    __syncthreads();

    for (int i = tid; i < cnt; i += 256) {
        int4 ed = tmp[base + i];
        int pos = atomicAdd(&fo[ed.z - node0], 1);
        csr[base + pos] = make_int2(ed.x, ed.y);
    }
}

// =====================================================================
// Propagation (bf16 state): zout = 0.9 * A zin + 0.1 * z0
// EXACT R0/R6 structure (proven ~97 us/layer; every structural
// alternative measured slower: R1 ILP x4 neutral, R2 206, R5 262,
// R7 173, R8 striped 210).  Row-major [N][64] state, wave per node,
// 8 lanes x 16 B full-row gathers, plain cached loads only.
// =====================================================================
__global__ __launch_bounds__(256) void prop_kernel(
    const int* __restrict__ rowptr, const int2* __restrict__ csr,
    const unsigned short* __restrict__ zin, const unsigned short* __restrict__ z0,
    unsigned short* __restrict__ zout_b, float* __restrict__ zout_f,
    int n, int final_layer)
{
    int lane = threadIdx.x & 63;
    int node = blockIdx.x * 4 + (threadIdx.x >> 6);
    if (node >= n) return;
    int beg = rowptr[node], end = rowptr[node + 1];
    const int sub = lane >> 3;
    const int k8  = lane & 7;

    float acc[8];
#pragma unroll
    for (int i = 0; i < 8; ++i) acc[i] = 0.f;

    for (int b = beg; b < end; b += 64) {
        int e = b + lane;
        int2 ed = (e < end) ? csr[e] : make_int2(0, 0);
        int cnt = end - b; if (cnt > 64) cnt = 64;
        int groups = (cnt + 7) >> 3;
        for (int j = 0; j < groups; ++j) {
            int idx = j * 8 + sub;
            int sj = __shfl(ed.x, idx);
            int wb = __shfl(ed.y, idx);
            if (idx < cnt) {
                float wj = __builtin_bit_cast(float, wb);
                uint4 v = *(const uint4*)(zin + (size_t)sj * 64 + k8 * 8);
                acc[0] += wj * blo(v.x); acc[1] += wj * bhi(v.x);
                acc[2] += wj * blo(v.y); acc[3] += wj * bhi(v.y);
                acc[4] += wj * blo(v.z); acc[5] += wj * bhi(v.z);
                acc[6] += wj * blo(v.w); acc[7] += wj * bhi(v.w);
            }
        }
    }
#pragma unroll
    for (int off = 8; off < 64; off <<= 1) {
#pragma unroll
        for (int i = 0; i < 8; ++i) acc[i] += __shfl_xor(acc[i], off);
    }
    if (sub == 0) {
        uint4 zv = *(const uint4*)(z0 + (size_t)node * 64 + k8 * 8);
        float o0 = 0.9f * acc[0] + 0.1f * blo(zv.x);
        float o1 = 0.9f * acc[1] + 0.1f * bhi(zv.x);
        float o2 = 0.9f * acc[2] + 0.1f * blo(zv.y);
        float o3 = 0.9f * acc[3] + 0.1f * bhi(zv.y);
        float o4 = 0.9f * acc[4] + 0.1f * blo(zv.z);
        float o5 = 0.9f * acc[5] + 0.1f * bhi(zv.z);
        float o6 = 0.9f * acc[6] + 0.1f * blo(zv.w);
        float o7 = 0.9f * acc[7] + 0.1f * bhi(zv.w);
        if (final_layer) {
            float* dp = zout_f + (size_t)node * 64 + k8 * 8;
            *(float4*)dp       = make_float4(o0, o1, o2, o3);
            *(float4*)(dp + 4) = make_float4(o4, o5, o6, o7);
        } else {
            uint4 pv;
            pv.x = cvtpk(o0, o1);
            pv.y = cvtpk(o2, o3);
            pv.z = cvtpk(o4, o5);
            pv.w = cvtpk(o6, o7);
            *(uint4*)(zout_b + (size_t)node * 64 + k8 * 8) = pv;
        }
    }
}

// =====================================================================
static inline size_t align_up(size_t v, size_t a) { return (v + a - 1) & ~(a - 1); }

extern "C" void kernel_launch(void* const* d_in, const int* in_sizes, int n_in,
                              void* d_out, int out_size, void* d_ws, size_t ws_size,
                              hipStream_t stream)
{
    const float* x     = (const float*)d_in[0];
    const float* W_in  = (const float*)d_in[1];
    const float* b_in  = (const float*)d_in[2];
    const float* W_out = (const float*)d_in[3];
    const float* b_out = (const float*)d_in[4];
    const int*   ei    = (const int*)d_in[5];     // [2,E]: src then dst
    const float* ew    = (const float*)d_in[6];

    const int N = in_sizes[0] / 512;              // 100000
    const int E = in_sizes[6];                    // 3200000
    const int* e_src = ei;
    const int* e_dst = ei + E;

    const int nbuk = (N + 511) >> 9;              // 196
    const int nblk = (E + CSR_CH - 1) / CSR_CH;   // 196

    // ---- workspace carve-up ----
    char* p = (char*)d_ws;
    size_t zbytes = align_up((size_t)N * 64 * sizeof(unsigned short), 256);
    unsigned short* z0b = (unsigned short*)p; p += zbytes;
    unsigned short* Wi_f = (unsigned short*)p; p += align_up(131072 * 2, 256);
    unsigned short* Wo_f = (unsigned short*)p; p += align_up(16384 * 2, 256);
    int2* csr   = (int2*)p; p += align_up((size_t)E * 8, 256);
    int* rowptr = (int*)p;  p += align_up((size_t)(N + 1) * 4, 256);
    int* M      = (int*)p;  p += align_up((size_t)nblk * nbuk * 4, 256);
    int* bucketBase = (int*)p; p += align_up((size_t)(nbuk + 1) * 4, 256);
    int4* tmp   = (int4*)p; p += align_up((size_t)E * 16, 256);
    unsigned short* zA = (unsigned short*)tmp;    // overlay (tmp dead after fine_sort)
    unsigned short* zB = zA + (size_t)N * 64;

    // ---- weights -> bf16 fragment order, then MLP -> z0 (bf16 row-major) ----
    wprep<<<(131072 + 16384 + 255) / 256, 256, 0, stream>>>(W_in, W_out, Wi_f, Wo_f);
    mlp<<<(N + 63) / 64, 256, 0, stream>>>(x, Wi_f, b_in, Wo_f, b_out, z0b, N);

    // ---- CSR build: 2-level counting sort ----
    coarse_hist<<<nblk, 256, 0, stream>>>(e_dst, M, E, nbuk);
    bucket_scan<<<1, 256, 0, stream>>>(M, bucketBase, nblk, nbuk);
    coarse_scatter<<<nblk, 256, 0, stream>>>(e_src, e_dst, ew, M, tmp, E, nbuk);
    fine_sort<<<nbuk, 256, 0, stream>>>(tmp, bucketBase, csr, rowptr, N, E);

    // ---- 10 propagation layers ----
    float* out_f = (float*)d_out;
    int pgrid = (N + 3) / 4;
    for (int i = 0; i < 10; ++i) {
        const unsigned short* zin = (i == 0) ? z0b : ((i & 1) ? zA : zB);
        unsigned short* zoutb = (i & 1) ? zB : zA;
        prop_kernel<<<pgrid, 256, 0, stream>>>(rowptr, csr, zin, z0b,
                                               zoutb, out_f, N, (i == 9) ? 1 : 0);
    }
}